// Round 8
// baseline (166.428 us; speedup 1.0000x reference)
//
#include <hip/hip_runtime.h>
#include <hip/hip_bf16.h>

#define KBOX 256
#define CCH  256
#define NODES 196
#define OS 14

typedef __attribute__((ext_vector_type(8))) short  bf16x8;
typedef __attribute__((ext_vector_type(8))) unsigned short u16x8;
typedef __attribute__((ext_vector_type(4))) float  f32x4;
typedef __attribute__((ext_vector_type(4))) short  s16x4;
typedef __attribute__((ext_vector_type(4))) int    i32x4;

__device__ __forceinline__ short f2bf(float x) {
  __hip_bfloat16 h = __float2bfloat16(x);
  return *reinterpret_cast<short*>(&h);
}
__device__ __forceinline__ float bf2f(unsigned short u) {
  unsigned int x = ((unsigned int)u) << 16;
  union { unsigned int i; float f; } c; c.i = x;
  return c.f;
}

#define MFMA16 __builtin_amdgcn_mfma_f32_16x16x32_bf16

// ---------------- prep: bn scale/shift, bf16 weight fragments ----------------
// wfrag : [kstep 144][nt 4][lane 64][e 8]   (3x3 convs, kstep = src*72 + icc*9 + pos)
// wafrag: [s 2][nt 13][lane 64][e 8]        (1x1 aff conv, 196 oc)
// g1wf  : [ks 8][lane 64][e 8]              (gcn1_w B-frags, K=256, N=16)
// g2wf  : [ct 16][lane 64][e 8]             (gcn2_w A-frags)
// ss_aff2: [0..63]=scale, [64..127]=(conv_sem_b+conv_fpn_b)*scale+shift
__global__ __launch_bounds__(256) void prep_kernel(
    const float* __restrict__ bn_sem_g, const float* __restrict__ bn_sem_b,
    const float* __restrict__ bn_sem_m, const float* __restrict__ bn_sem_v,
    const float* __restrict__ conv_sem_w, const float* __restrict__ conv_sem_b,
    const float* __restrict__ bn_fpn_g, const float* __restrict__ bn_fpn_b,
    const float* __restrict__ bn_fpn_m, const float* __restrict__ bn_fpn_v,
    const float* __restrict__ conv_fpn_w, const float* __restrict__ conv_fpn_b,
    const float* __restrict__ bn_aff_g, const float* __restrict__ bn_aff_b,
    const float* __restrict__ bn_aff_m, const float* __restrict__ bn_aff_v,
    const float* __restrict__ conv_aff_w, const float* __restrict__ g1w,
    const float* __restrict__ g2w,
    float* __restrict__ ss_sem, float* __restrict__ ss_fpn, float* __restrict__ ss_aff2,
    short* __restrict__ wfrag, short* __restrict__ wafrag, short* __restrict__ g1wf,
    short* __restrict__ g2wf)
{
  int gid = blockIdx.x * blockDim.x + threadIdx.x;
  int gsz = gridDim.x * blockDim.x;
  for (int c = gid; c < 256; c += gsz) {
    float s = bn_sem_g[c] * rsqrtf(bn_sem_v[c] + 1e-5f);
    ss_sem[c] = s; ss_sem[256 + c] = bn_sem_b[c] - bn_sem_m[c] * s;
    float s2 = bn_fpn_g[c] * rsqrtf(bn_fpn_v[c] + 1e-5f);
    ss_fpn[c] = s2; ss_fpn[256 + c] = bn_fpn_b[c] - bn_fpn_m[c] * s2;
  }
  for (int c = gid; c < 64; c += gsz) {
    float s = bn_aff_g[c] * rsqrtf(bn_aff_v[c] + 1e-5f);
    float sh = bn_aff_b[c] - bn_aff_m[c] * s;
    float bias = conv_sem_b[c] + conv_fpn_b[c];
    ss_aff2[c] = s; ss_aff2[64 + c] = bias * s + sh;
  }
  for (int idx = gid; idx < 144 * 4 * 64 * 8; idx += gsz) {
    int e = idx & 7, lane = (idx >> 3) & 63, nt = (idx >> 9) & 3, kstep = idx >> 11;
    int src = kstep / 72, rem = kstep % 72, icc = rem / 9, pos = rem % 9;
    int ky = pos / 3, kx = pos % 3;
    int oc = nt * 16 + (lane & 15);
    int ic = icc * 32 + (lane >> 4) * 8 + e;
    const float* w = src ? conv_fpn_w : conv_sem_w;
    wfrag[idx] = f2bf(w[((oc * 256 + ic) * 3 + ky) * 3 + kx]);
  }
  for (int idx = gid; idx < 2 * 13 * 64 * 8; idx += gsz) {
    int t = idx;
    int e = t & 7; t >>= 3;
    int lane = t & 63; t >>= 6;
    int nt = t % 13; int s = t / 13;
    int i = nt * 16 + (lane & 15);
    int ic = s * 32 + (lane >> 4) * 8 + e;
    wafrag[idx] = f2bf(i < NODES ? conv_aff_w[i * 64 + ic] : 0.f);
  }
  for (int idx = gid; idx < 8 * 64 * 8; idx += gsz) {
    int e = idx & 7, lane = (idx >> 3) & 63, ks = idx >> 9;
    int ic = ks * 32 + (lane >> 4) * 8 + e;
    int f = lane & 15;
    g1wf[idx] = f2bf(g1w[ic * 16 + f]);
  }
  for (int idx = gid; idx < 16 * 64 * 8; idx += gsz) {
    int e = idx & 7, lane = (idx >> 3) & 63, ct = idx >> 9;
    int kk = (lane >> 4) * 8 + e;
    int c = ct * 16 + (lane & 15);
    g2wf[idx] = f2bf(kk < 16 ? g2w[kk * 256 + c] : 0.f);
  }
}

// ---------------- NCHW f32 -> NHWC bf16 transpose (64x64 LDS tiles) ----------------
__global__ __launch_bounds__(256) void transpose_bf16_kernel(
    const float* __restrict__ in, unsigned short* __restrict__ out, int C, int HW)
{
  __shared__ float tile[64][65];
  int nh = (HW + 63) >> 6;
  int bi = blockIdx.x;
  int cb = bi % (C >> 6); bi /= (C >> 6);
  int hb = bi % nh; int b = bi / nh;
  int tx = threadIdx.x & 63, ty = threadIdx.x >> 6;
  const float* inb = in + (size_t)b * C * HW;
  unsigned short* outb = out + (size_t)b * HW * C;
  #pragma unroll
  for (int i = ty; i < 64; i += 4) {
    int c = cb * 64 + i, hw = hb * 64 + tx;
    tile[i][tx] = (hw < HW) ? inb[(size_t)c * HW + hw] : 0.f;
  }
  __syncthreads();
  int cp = threadIdx.x & 31;
  #pragma unroll
  for (int i = (int)(threadIdx.x >> 5); i < 64; i += 8) {
    int hw = hb * 64 + i;
    if (hw < HW) {
      ushort2 v;
      v.x = (unsigned short)f2bf(tile[cp * 2][i]);
      v.y = (unsigned short)f2bf(tile[cp * 2 + 1][i]);
      *(ushort2*)&outb[(size_t)hw * C + cb * 64 + cp * 2] = v;
    }
  }
}

// ---------------- roi_align from NHWC bf16 semantic ----------------
__global__ __launch_bounds__(512) void roi_align_kernel(
    const unsigned short* __restrict__ semt, const float* __restrict__ boxes,
    unsigned short* __restrict__ roi_sem)
{
  __shared__ unsigned short slab[5][29][256];   // 74,240 B
  int kb = blockIdx.x / 7, g = blockIdx.x % 7;
  int tid = threadIdx.x, wave = tid >> 6, lane = tid & 63;
  const float* bx = boxes + kb * 5;
  int bb = (int)bx[0];
  float x1 = bx[1], y1 = bx[2];
  float xb = x1 + 0.5f, yv = y1 + 0.5f;
  int X0 = (int)floorf(xb); float fx = xb - (float)X0;
  int Y0 = (int)floorf(yv); float fy = yv - (float)Y0;
  const unsigned short* base = semt + (size_t)bb * 12544 * 256;
  #pragma unroll
  for (int i = 0; i < 19; ++i) {
    int s = wave + i * 8;
    if (s < 145) {
      int r = s / 29, xi = s - r * 29;
      int yr = min(Y0 + 4 * g + r, 111);
      int xc = min(X0 + xi, 111);
      *(s16x4*)&slab[r][xi][lane * 4] =
          *(const s16x4*)(base + ((size_t)yr * 112 + xc) * 256 + lane * 4);
    }
  }
  __syncthreads();
  int c2 = tid & 127, grp = tid >> 7;
  int oyl = grp >> 1, og = grp & 1;
  int rb = oyl * 2;
  float w0 = 1.f - fy;
  unsigned short* op = roi_sem + (((size_t)kb * NODES) + (2 * g + oyl) * OS) * 256 + c2 * 2;
  #pragma unroll
  for (int oxs = 0; oxs < 7; ++oxs) {
    int ox = og * 7 + oxs;
    float o0 = 0.f, o1 = 0.f;
    #pragma unroll
    for (int xi = 0; xi < 3; ++xi) {
      float xw = (xi == 0) ? (1.f - fx) : (xi == 1 ? 1.f : fx);
      const unsigned short* p0 = &slab[rb][2 * ox + xi][c2 * 2];
      const unsigned short* p1 = &slab[rb + 1][2 * ox + xi][c2 * 2];
      const unsigned short* p2 = &slab[rb + 2][2 * ox + xi][c2 * 2];
      o0 += xw * (w0 * bf2f(p0[0]) + bf2f(p1[0]) + fy * bf2f(p2[0]));
      o1 += xw * (w0 * bf2f(p0[1]) + bf2f(p1[1]) + fy * bf2f(p2[1]));
    }
    ushort2 v;
    v.x = (unsigned short)f2bf(o0 * 0.25f);
    v.y = (unsigned short)f2bf(o1 * 0.25f);
    *(ushort2*)(op + (size_t)ox * 256) = v;
  }
}

// ---------------- bn_relu + dual 3x3 conv, pos-split waves -> bn_aff_relu bf16 ----------------
// 8 waves = (pg in [0,4) owning filter-pos set {0,1,2}/{3,4}/{5,6}/{7,8}; ng in [0,2) owning
// oc-tiles {2ng, 2ng+1}). Each (pos,nt) weight frag read ONCE per block, direct from global
// (L2-resident). Input staged once per src in LDS (stride 268 -> ~2-way). Partial sums
// reduced across pg via LDS f32 tree. Cuts LDS instrs ~1.7x vs per-phase staging.
__global__ __launch_bounds__(512) void conv_ab_kernel(
    const unsigned short* __restrict__ roi_sem, const unsigned short* __restrict__ roif,
    const float* __restrict__ ss_sem, const float* __restrict__ ss_fpn,
    const float* __restrict__ ss_aff2, const short* __restrict__ wfrag,
    short* __restrict__ a_rel)
{
  __shared__ short inLDS[198 * 268];      // 106,128 B; rows 0..195 input, 196 zero pad
  __shared__ float scA[64], cmbA[64];
  const int k = blockIdx.x;
  const int tid = threadIdx.x;
  const int wave = tid >> 6, lane = tid & 63;
  const int l15 = lane & 15, lq = lane >> 4;
  const int pg = wave >> 1, ng = wave & 1;
  const int p0 = (pg == 0) ? 0 : (pg * 2 + 1);
  const int p1 = p0 + ((pg == 0) ? 3 : 2);

  if (tid < 64) { scA[tid] = ss_aff2[tid]; cmbA[tid] = ss_aff2[64 + tid]; }
  if (tid < 34) {
    bf16x8 z = {};
    *(bf16x8*)&inLDS[196 * 268 + tid * 8] = z;   // spills into row 197 scratch
  }

  int oyA[13], oxA[13];
  #pragma unroll
  for (int mt = 0; mt < 13; ++mt) {
    int j = mt * 16 + l15;
    int oy = j / 14;
    oyA[mt] = oy; oxA[mt] = j - oy * 14;
  }
  const int c0 = (tid & 31) * 8;

  f32x4 acc[13][2];
  #pragma unroll
  for (int mt = 0; mt < 13; ++mt) {
    acc[mt][0] = f32x4{0.f, 0.f, 0.f, 0.f};
    acc[mt][1] = f32x4{0.f, 0.f, 0.f, 0.f};
  }

  for (int src = 0; src < 2; ++src) {
    const unsigned short* inp = (src ? roif : roi_sem) + (size_t)k * NODES * CCH;
    const float* ss = src ? ss_fpn : ss_sem;
    f32x4 sc0 = *(const f32x4*)(ss + c0);
    f32x4 sc1 = *(const f32x4*)(ss + c0 + 4);
    f32x4 sh0 = *(const f32x4*)(ss + 256 + c0);
    f32x4 sh1 = *(const f32x4*)(ss + 256 + c0 + 4);
    __syncthreads();            // all waves done reading previous staging
    #pragma unroll
    for (int i = 0; i < 12; ++i) {
      int j = (tid >> 5) + i * 16;
      u16x8 v = *(const u16x8*)(inp + (size_t)j * 256 + c0);
      bf16x8 pk;
      #pragma unroll
      for (int u = 0; u < 4; ++u) pk[u] = f2bf(fmaxf(bf2f(v[u]) * sc0[u] + sh0[u], 0.f));
      #pragma unroll
      for (int u = 0; u < 4; ++u) pk[4 + u] = f2bf(fmaxf(bf2f(v[4 + u]) * sc1[u] + sh1[u], 0.f));
      *(bf16x8*)&inLDS[j * 268 + c0] = pk;
    }
    if (tid < 128) {
      int j = 192 + (tid >> 5);
      u16x8 v = *(const u16x8*)(inp + (size_t)j * 256 + c0);
      bf16x8 pk;
      #pragma unroll
      for (int u = 0; u < 4; ++u) pk[u] = f2bf(fmaxf(bf2f(v[u]) * sc0[u] + sh0[u], 0.f));
      #pragma unroll
      for (int u = 0; u < 4; ++u) pk[4 + u] = f2bf(fmaxf(bf2f(v[4 + u]) * sc1[u] + sh1[u], 0.f));
      *(bf16x8*)&inLDS[j * 268 + c0] = pk;
    }
    __syncthreads();

    for (int pos = p0; pos < p1; ++pos) {
      int ky = pos / 3 - 1, kx = pos % 3 - 1;       // wave-uniform
      int np[13];
      #pragma unroll
      for (int mt = 0; mt < 13; ++mt) {
        int ny = oyA[mt] + ky, nx = oxA[mt] + kx;
        bool v = ((unsigned)ny < 14u) & ((unsigned)nx < 14u) & ((mt * 16 + l15) < 196);
        np[mt] = v ? (ny * 14 + nx) : 196;
      }
      #pragma unroll
      for (int icc = 0; icc < 8; ++icc) {
        const short* wp = wfrag +
            ((size_t)((src * 72 + icc * 9 + pos) * 4 + ng * 2) * 64 + lane) * 8;
        bf16x8 b0 = *(const bf16x8*)wp;
        bf16x8 b1 = *(const bf16x8*)(wp + 512);
        #pragma unroll
        for (int mt = 0; mt < 13; ++mt) {
          bf16x8 a = *(const bf16x8*)&inLDS[np[mt] * 268 + icc * 32 + lq * 8];
          acc[mt][0] = MFMA16(a, b0, acc[mt][0], 0, 0, 0);
          acc[mt][1] = MFMA16(a, b1, acc[mt][1], 0, 0, 0);
        }
      }
    }
  }

  // ---- cross-pg reduction: pg1->buf0[ng], pg3->buf1[ng]; pg0+=buf0, pg2+=buf1;
  //      pg2->buf0[ng]; pg0+=buf0; pg0 applies bn_aff relu and writes a_rel ----
  float* red = (float*)inLDS;           // [2 buf][2 ng][196][32] f32 = 100,352 B
  __syncthreads();
  if (pg == 1 || pg == 3) {
    float* dst = red + (size_t)((pg >> 1) * 2 + ng) * 6272;
    #pragma unroll
    for (int mt = 0; mt < 13; ++mt)
      #pragma unroll
      for (int nn = 0; nn < 2; ++nn)
        #pragma unroll
        for (int r = 0; r < 4; ++r) {
          int j = mt * 16 + lq * 4 + r;
          if (j < 196) dst[j * 32 + nn * 16 + l15] = acc[mt][nn][r];
        }
  }
  __syncthreads();
  if (pg == 0 || pg == 2) {
    const float* sb = red + (size_t)((pg >> 1) * 2 + ng) * 6272;
    #pragma unroll
    for (int mt = 0; mt < 13; ++mt)
      #pragma unroll
      for (int nn = 0; nn < 2; ++nn)
        #pragma unroll
        for (int r = 0; r < 4; ++r) {
          int j = mt * 16 + lq * 4 + r;
          if (j < 196) acc[mt][nn][r] += sb[j * 32 + nn * 16 + l15];
        }
  }
  __syncthreads();
  if (pg == 2) {
    float* dst = red + (size_t)ng * 6272;
    #pragma unroll
    for (int mt = 0; mt < 13; ++mt)
      #pragma unroll
      for (int nn = 0; nn < 2; ++nn)
        #pragma unroll
        for (int r = 0; r < 4; ++r) {
          int j = mt * 16 + lq * 4 + r;
          if (j < 196) dst[j * 32 + nn * 16 + l15] = acc[mt][nn][r];
        }
  }
  __syncthreads();
  if (pg == 0) {
    const float* sb = red + (size_t)ng * 6272;
    short* op = a_rel + (size_t)k * 12544;
    #pragma unroll
    for (int mt = 0; mt < 13; ++mt)
      #pragma unroll
      for (int nn = 0; nn < 2; ++nn) {
        int oc = (ng * 2 + nn) * 16 + l15;
        float sa = scA[oc], cb = cmbA[oc];
        #pragma unroll
        for (int r = 0; r < 4; ++r) {
          int j = mt * 16 + lq * 4 + r;
          if (j < 196) {
            float t = acc[mt][nn][r] + sb[j * 32 + nn * 16 + l15];
            op[j * 64 + oc] = f2bf(fmaxf(t * sa + cb, 0.f));
          }
        }
      }
  }
}

// ---------------- fused graph kernel: aff+sigmoid+deg + xw1 + agg1 + agg2 + MFMA epilogue ----------------
__global__ __launch_bounds__(1024, 1) void graph_kernel(
    const short* __restrict__ a_rel, const short* __restrict__ wafrag,
    const float* __restrict__ aff_b, const short* __restrict__ g1wf,
    const float* __restrict__ g1b, const unsigned short* __restrict__ roif_bf,
    const short* __restrict__ g2wf, const float* __restrict__ g2b,
    const unsigned short* __restrict__ roi_sem, float* __restrict__ outp)
{
  __shared__ __align__(16) char smem[125840];
  const int tid = threadIdx.x, wave = tid >> 6, lane = tid & 63;
  const int l15 = lane & 15, lq = lane >> 4;
  const int k = blockIdx.x;

  char*  Ab   = smem;                       // [208][464 B] bf16 A^T (row j, col i)
  short* wa   = (short*)(smem + 96512);     // 26,624 B  [P0..P1]
  short* yfr  = (short*)(smem + 96512);     // 7,168 B   [post-P1, overlays wa]
  short* zsf  = (short*)(smem + 103680);    // 13,312 B  [post-P1, overlays wa]
  float* dsl  = (float*)(smem + 123136);    // 208 f32
  float* g1bl = (float*)(smem + 123968);    // 16 f32
  float* g2bl = (float*)(smem + 124032);    // 256 f32
  float* affb = (float*)(smem + 125056);    // 196 f32

  const bool wv13 = (wave < 13);
  const int jr  = wave * 16 + l15;
  const int jrc = min(jr, 195);
  const i32x4 z4 = {};

  // ---------- P0: a-frags to regs; stage wa; zero Ab pad cols; stage biases ----------
  bf16x8 af0 = {}, af1 = {};
  if (wv13) {
    const short* ap = a_rel + (size_t)k * 12544 + jrc * 64 + lq * 8;
    af0 = *(const bf16x8*)ap;
    af1 = *(const bf16x8*)(ap + 32);
  }
  {
    i32x4 w0 = ((const i32x4*)wafrag)[tid];
    i32x4 w1 = z4;
    if (tid < 640) w1 = ((const i32x4*)wafrag)[1024 + tid];
    if (tid < 832) {
      int r = tid >> 2, q = tid & 3;
      *(i32x4*)(Ab + r * 464 + 384 + q * 16) = z4;
    }
    if (tid < 196) affb[tid] = aff_b[tid];
    if (tid < 256) g2bl[tid] = g2b[tid];
    if (tid < 16)  g1bl[tid] = g1b[tid];
    ((i32x4*)wa)[tid] = w0;
    if (tid < 640) ((i32x4*)wa)[1024 + tid] = w1;
  }
  __syncthreads();

  // ---------- P1: aff 1x1 conv + sigmoid -> Ab; rowsum -> dsl ----------
  if (wv13) {
    float rsum[4] = {0.f, 0.f, 0.f, 0.f};
    #pragma unroll
    for (int n = 0; n < 13; ++n) {
      bf16x8 b0 = *(const bf16x8*)(wa + (n * 64 + lane) * 8);
      bf16x8 b1 = *(const bf16x8*)(wa + ((13 + n) * 64 + lane) * 8);
      f32x4 acc = {0.f, 0.f, 0.f, 0.f};
      acc = MFMA16(af0, b0, acc, 0, 0, 0);
      acc = MFMA16(af1, b1, acc, 0, 0, 0);
      int i = n * 16 + l15;
      bool iv = (i < 196);
      float bv = affb[iv ? i : 0];
      #pragma unroll
      for (int r = 0; r < 4; ++r) {
        float v = acc[r] + bv;
        float s = 1.f / (1.f + __expf(-v));
        if (iv) {
          rsum[r] += s;
          *(short*)(Ab + (wave * 16 + lq * 4 + r) * 464 + i * 2) = f2bf(s);
        }
      }
    }
    #pragma unroll
    for (int r = 0; r < 4; ++r) {
      float v = rsum[r];
      v += __shfl_xor(v, 1); v += __shfl_xor(v, 2);
      v += __shfl_xor(v, 4); v += __shfl_xor(v, 8);
      int j = wave * 16 + lq * 4 + r;
      if (l15 == 0 && j < 196) dsl[j] = rsqrtf(v);
    }
  }
  __syncthreads();

  // ---------- P2/P3: zero yfr+zsf; xw1 = X @ g1w (direct global frags) ----------
  *(i32x4*)(smem + 96512 + tid * 16) = z4;
  if (tid < 256) *(i32x4*)(smem + 96512 + (1024 + tid) * 16) = z4;
  f32x4 xacc = {0.f, 0.f, 0.f, 0.f};
  if (wv13) {
    const unsigned short* Xp = roif_bf + (size_t)k * 50176 + (size_t)jrc * 256 + lq * 8;
    #pragma unroll
    for (int ks = 0; ks < 8; ++ks) {
      bf16x8 xa = *(const bf16x8*)(Xp + ks * 32);
      bf16x8 xb = *(const bf16x8*)(g1wf + (ks * 64 + lane) * 8);
      xacc = MFMA16(xa, xb, xacc, 0, 0, 0);
    }
  }
  __syncthreads();

  // ---------- P4: y = dis*xw1 -> yfr B-frags ----------
  if (wv13) {
    #pragma unroll
    for (int r = 0; r < 4; ++r) {
      int i = wave * 16 + lq * 4 + r;
      if (i < 196) {
        float yv = dsl[i] * xacc[r];
        yfr[((i >> 5) * 64 + ((i >> 3) & 3) * 16 + l15) * 8 + (i & 7)] = f2bf(yv);
      }
    }
  }
  __syncthreads();

  // ---------- P5: agg1 ----------
  f32x4 g0 = {0.f, 0.f, 0.f, 0.f};
  if (wv13) {
    #pragma unroll
    for (int ks = 0; ks < 7; ++ks) {
      bf16x8 bb = *(const bf16x8*)(yfr + (ks * 64 + lane) * 8);
      bf16x8 a0 = *(const bf16x8*)(Ab + jr * 464 + ks * 64 + lq * 16);
      g0 = MFMA16(a0, bb, g0, 0, 0, 0);
    }
  }
  __syncthreads();
  if (wv13) {
    #pragma unroll
    for (int r = 0; r < 4; ++r) {
      int i = wave * 16 + lq * 4 + r;
      if (i < 196) {
        float d = dsl[i];
        float x1v = fmaxf(g0[r] * d + g1bl[l15], 0.f);
        yfr[((i >> 5) * 64 + ((i >> 3) & 3) * 16 + l15) * 8 + (i & 7)] = f2bf(d * x1v);
      }
    }
  }
  __syncthreads();

  // ---------- P6: agg2 -> zs (dis-scaled) -> zsf B-frags ----------
  if (wv13) {
    f32x4 z0 = {0.f, 0.f, 0.f, 0.f};
    #pragma unroll
    for (int ks = 0; ks < 7; ++ks) {
      bf16x8 bb = *(const bf16x8*)(yfr + (ks * 64 + lane) * 8);
      bf16x8 a0 = *(const bf16x8*)(Ab + jr * 464 + ks * 64 + lq * 16);
      z0 = MFMA16(a0, bb, z0, 0, 0, 0);
    }
    #pragma unroll
    for (int r = 0; r < 4; ++r) {
      int j = wave * 16 + lq * 4 + r;
      if (j < 196) {
        float zv = z0[r] * dsl[j];
        zsf[((j >> 4) * 64 + (l15 >> 3) * 16 + (j & 15)) * 8 + (l15 & 7)] = f2bf(zv);
      }
    }
  }
  __syncthreads();

  // ---------- P7: out[k,c,j] = mfma(w2_frag, zs_frag) + g2b[c] + roi_sem[k,j,c] ----------
  {
    bf16x8 wf = *(const bf16x8*)(g2wf + (wave * 64 + lane) * 8);
    const unsigned short* rsmk = roi_sem + (size_t)k * 50176;
    float* op = outp + (size_t)k * 50176;
    float gbv[4];
    #pragma unroll
    for (int r = 0; r < 4; ++r) gbv[r] = g2bl[wave * 16 + lq * 4 + r];
    #pragma unroll
    for (int jt = 0; jt < 13; ++jt) {
      bf16x8 zb = *(const bf16x8*)(zsf + (jt * 64 + lane) * 8);
      f32x4 d = {0.f, 0.f, 0.f, 0.f};
      d = MFMA16(wf, zb, d, 0, 0, 0);
      int j = jt * 16 + l15;
      if (j < 196) {
        #pragma unroll
        for (int r = 0; r < 4; ++r) {
          int c = wave * 16 + lq * 4 + r;
          op[(size_t)c * 196 + j] = d[r] + gbv[r] + bf2f(rsmk[(size_t)j * 256 + c]);
        }
      }
    }
  }
}

extern "C" void kernel_launch(void* const* d_in, const int* in_sizes, int n_in,
                              void* d_out, int out_size, void* d_ws, size_t ws_size,
                              hipStream_t stream) {
  const float* roi_feature = (const float*)d_in[0];
  const float* semantic    = (const float*)d_in[1];
  const float* boxes       = (const float*)d_in[2];
  const float* bn_sem_g = (const float*)d_in[3];
  const float* bn_sem_b = (const float*)d_in[4];
  const float* bn_sem_m = (const float*)d_in[5];
  const float* bn_sem_v = (const float*)d_in[6];
  const float* conv_sem_w = (const float*)d_in[7];
  const float* conv_sem_b = (const float*)d_in[8];
  const float* bn_fpn_g = (const float*)d_in[9];
  const float* bn_fpn_b = (const float*)d_in[10];
  const float* bn_fpn_m = (const float*)d_in[11];
  const float* bn_fpn_v = (const float*)d_in[12];
  const float* conv_fpn_w = (const float*)d_in[13];
  const float* conv_fpn_b = (const float*)d_in[14];
  const float* bn_aff_g = (const float*)d_in[15];
  const float* bn_aff_b = (const float*)d_in[16];
  const float* bn_aff_m = (const float*)d_in[17];
  const float* bn_aff_v = (const float*)d_in[18];
  const float* conv_aff_w = (const float*)d_in[19];
  const float* conv_aff_b = (const float*)d_in[20];
  const float* gcn1_w = (const float*)d_in[21];
  const float* gcn1_b = (const float*)d_in[22];
  const float* gcn2_w = (const float*)d_in[23];
  const float* gcn2_b = (const float*)d_in[24];

  const size_t FT = (size_t)KBOX * NODES * CCH;       // 12,845,056 elements
  unsigned short* ws16      = (unsigned short*)d_ws;
  unsigned short* semt_bf   = ws16;                    // FT shorts
  unsigned short* roif_bf   = semt_bf + FT;
  unsigned short* roi_sem_b = roif_bf + FT;
  short*          a_rel     = (short*)(roi_sem_b + FT);          // 3,211,264 shorts
  float*          ss_sem    = (float*)(a_rel + 3211264);         // 512
  float*          ss_fpn    = ss_sem + 512;                      // 512
  float*          ss_aff2   = ss_fpn + 512;                      // 128
  short*          wfrag     = (short*)(ss_aff2 + 128);           // 294,912
  short*          wafrag    = wfrag + 294912;                    // 13,312
  short*          g1wf      = wafrag + 13312;                    // 4,096
  short*          g2wf      = g1wf + 4096;                       // 8,192

  prep_kernel<<<256, 256, 0, stream>>>(
      bn_sem_g, bn_sem_b, bn_sem_m, bn_sem_v, conv_sem_w, conv_sem_b,
      bn_fpn_g, bn_fpn_b, bn_fpn_m, bn_fpn_v, conv_fpn_w, conv_fpn_b,
      bn_aff_g, bn_aff_b, bn_aff_m, bn_aff_v, conv_aff_w, gcn1_w, gcn2_w,
      ss_sem, ss_fpn, ss_aff2, wfrag, wafrag, g1wf, g2wf);

  transpose_bf16_kernel<<<4 * 196 * 4, 256, 0, stream>>>(semantic, semt_bf, 256, 12544);
  transpose_bf16_kernel<<<4 * 4 * 256, 256, 0, stream>>>(roi_feature, roif_bf, 256, 196);
  roi_align_kernel<<<KBOX * 7, 512, 0, stream>>>(semt_bf, boxes, roi_sem_b);
  conv_ab_kernel<<<KBOX, 512, 0, stream>>>(roi_sem_b, roif_bf, ss_sem, ss_fpn, ss_aff2,
                                           wfrag, a_rel);
  graph_kernel<<<KBOX, 1024, 0, stream>>>(a_rel, wafrag, conv_aff_b, g1wf, gcn1_b, roif_bf,
                                          g2wf, gcn2_b, roi_sem_b, (float*)d_out);
}

// Round 9
// 160.451 us; speedup vs baseline: 1.0373x; 1.0373x over previous
//
#include <hip/hip_runtime.h>
#include <hip/hip_bf16.h>

#define KBOX 256
#define CCH  256
#define NODES 196
#define OS 14

typedef __attribute__((ext_vector_type(8))) short  bf16x8;
typedef __attribute__((ext_vector_type(8))) unsigned short u16x8;
typedef __attribute__((ext_vector_type(4))) float  f32x4;
typedef __attribute__((ext_vector_type(4))) short  s16x4;
typedef __attribute__((ext_vector_type(4))) int    i32x4;

__device__ __forceinline__ short f2bf(float x) {
  __hip_bfloat16 h = __float2bfloat16(x);
  return *reinterpret_cast<short*>(&h);
}
__device__ __forceinline__ float bf2f(unsigned short u) {
  unsigned int x = ((unsigned int)u) << 16;
  union { unsigned int i; float f; } c; c.i = x;
  return c.f;
}

#define MFMA16 __builtin_amdgcn_mfma_f32_16x16x32_bf16

// ---------------- prep: bn scale/shift, bf16 weight fragments ----------------
// wfrag : [kstep 144][nt 4][lane 64][e 8]   (3x3 convs, kstep = src*72 + icc*9 + pos)
// wafrag: [s 2][nt 13][lane 64][e 8]        (1x1 aff conv, 196 oc)
// g1wf  : [ks 8][lane 64][e 8]              (gcn1_w B-frags, K=256, N=16)
// g2wf  : [ct 16][lane 64][e 8]             (gcn2_w A-frags)
// ss_aff2: [0..63]=scale, [64..127]=(conv_sem_b+conv_fpn_b)*scale+shift
__global__ __launch_bounds__(256) void prep_kernel(
    const float* __restrict__ bn_sem_g, const float* __restrict__ bn_sem_b,
    const float* __restrict__ bn_sem_m, const float* __restrict__ bn_sem_v,
    const float* __restrict__ conv_sem_w, const float* __restrict__ conv_sem_b,
    const float* __restrict__ bn_fpn_g, const float* __restrict__ bn_fpn_b,
    const float* __restrict__ bn_fpn_m, const float* __restrict__ bn_fpn_v,
    const float* __restrict__ conv_fpn_w, const float* __restrict__ conv_fpn_b,
    const float* __restrict__ bn_aff_g, const float* __restrict__ bn_aff_b,
    const float* __restrict__ bn_aff_m, const float* __restrict__ bn_aff_v,
    const float* __restrict__ conv_aff_w, const float* __restrict__ g1w,
    const float* __restrict__ g2w,
    float* __restrict__ ss_sem, float* __restrict__ ss_fpn, float* __restrict__ ss_aff2,
    short* __restrict__ wfrag, short* __restrict__ wafrag, short* __restrict__ g1wf,
    short* __restrict__ g2wf)
{
  int gid = blockIdx.x * blockDim.x + threadIdx.x;
  int gsz = gridDim.x * blockDim.x;
  for (int c = gid; c < 256; c += gsz) {
    float s = bn_sem_g[c] * rsqrtf(bn_sem_v[c] + 1e-5f);
    ss_sem[c] = s; ss_sem[256 + c] = bn_sem_b[c] - bn_sem_m[c] * s;
    float s2 = bn_fpn_g[c] * rsqrtf(bn_fpn_v[c] + 1e-5f);
    ss_fpn[c] = s2; ss_fpn[256 + c] = bn_fpn_b[c] - bn_fpn_m[c] * s2;
  }
  for (int c = gid; c < 64; c += gsz) {
    float s = bn_aff_g[c] * rsqrtf(bn_aff_v[c] + 1e-5f);
    float sh = bn_aff_b[c] - bn_aff_m[c] * s;
    float bias = conv_sem_b[c] + conv_fpn_b[c];
    ss_aff2[c] = s; ss_aff2[64 + c] = bias * s + sh;
  }
  for (int idx = gid; idx < 144 * 4 * 64 * 8; idx += gsz) {
    int e = idx & 7, lane = (idx >> 3) & 63, nt = (idx >> 9) & 3, kstep = idx >> 11;
    int src = kstep / 72, rem = kstep % 72, icc = rem / 9, pos = rem % 9;
    int ky = pos / 3, kx = pos % 3;
    int oc = nt * 16 + (lane & 15);
    int ic = icc * 32 + (lane >> 4) * 8 + e;
    const float* w = src ? conv_fpn_w : conv_sem_w;
    wfrag[idx] = f2bf(w[((oc * 256 + ic) * 3 + ky) * 3 + kx]);
  }
  for (int idx = gid; idx < 2 * 13 * 64 * 8; idx += gsz) {
    int t = idx;
    int e = t & 7; t >>= 3;
    int lane = t & 63; t >>= 6;
    int nt = t % 13; int s = t / 13;
    int i = nt * 16 + (lane & 15);
    int ic = s * 32 + (lane >> 4) * 8 + e;
    wafrag[idx] = f2bf(i < NODES ? conv_aff_w[i * 64 + ic] : 0.f);
  }
  for (int idx = gid; idx < 8 * 64 * 8; idx += gsz) {
    int e = idx & 7, lane = (idx >> 3) & 63, ks = idx >> 9;
    int ic = ks * 32 + (lane >> 4) * 8 + e;
    int f = lane & 15;
    g1wf[idx] = f2bf(g1w[ic * 16 + f]);
  }
  for (int idx = gid; idx < 16 * 64 * 8; idx += gsz) {
    int e = idx & 7, lane = (idx >> 3) & 63, ct = idx >> 9;
    int kk = (lane >> 4) * 8 + e;
    int c = ct * 16 + (lane & 15);
    g2wf[idx] = f2bf(kk < 16 ? g2w[kk * 256 + c] : 0.f);
  }
}

// ---------------- NCHW f32 -> NHWC bf16 transpose (64x64 LDS tiles) ----------------
__global__ __launch_bounds__(256) void transpose_bf16_kernel(
    const float* __restrict__ in, unsigned short* __restrict__ out, int C, int HW)
{
  __shared__ float tile[64][65];
  int nh = (HW + 63) >> 6;
  int bi = blockIdx.x;
  int cb = bi % (C >> 6); bi /= (C >> 6);
  int hb = bi % nh; int b = bi / nh;
  int tx = threadIdx.x & 63, ty = threadIdx.x >> 6;
  const float* inb = in + (size_t)b * C * HW;
  unsigned short* outb = out + (size_t)b * HW * C;
  #pragma unroll
  for (int i = ty; i < 64; i += 4) {
    int c = cb * 64 + i, hw = hb * 64 + tx;
    tile[i][tx] = (hw < HW) ? inb[(size_t)c * HW + hw] : 0.f;
  }
  __syncthreads();
  int cp = threadIdx.x & 31;
  #pragma unroll
  for (int i = (int)(threadIdx.x >> 5); i < 64; i += 8) {
    int hw = hb * 64 + i;
    if (hw < HW) {
      ushort2 v;
      v.x = (unsigned short)f2bf(tile[cp * 2][i]);
      v.y = (unsigned short)f2bf(tile[cp * 2 + 1][i]);
      *(ushort2*)&outb[(size_t)hw * C + cb * 64 + cp * 2] = v;
    }
  }
}

// ---------------- roi_align from NHWC bf16 semantic ----------------
__global__ __launch_bounds__(512) void roi_align_kernel(
    const unsigned short* __restrict__ semt, const float* __restrict__ boxes,
    unsigned short* __restrict__ roi_sem)
{
  __shared__ unsigned short slab[5][29][256];   // 74,240 B
  int kb = blockIdx.x / 7, g = blockIdx.x % 7;
  int tid = threadIdx.x, wave = tid >> 6, lane = tid & 63;
  const float* bx = boxes + kb * 5;
  int bb = (int)bx[0];
  float x1 = bx[1], y1 = bx[2];
  float xb = x1 + 0.5f, yv = y1 + 0.5f;
  int X0 = (int)floorf(xb); float fx = xb - (float)X0;
  int Y0 = (int)floorf(yv); float fy = yv - (float)Y0;
  const unsigned short* base = semt + (size_t)bb * 12544 * 256;
  #pragma unroll
  for (int i = 0; i < 19; ++i) {
    int s = wave + i * 8;
    if (s < 145) {
      int r = s / 29, xi = s - r * 29;
      int yr = min(Y0 + 4 * g + r, 111);
      int xc = min(X0 + xi, 111);
      *(s16x4*)&slab[r][xi][lane * 4] =
          *(const s16x4*)(base + ((size_t)yr * 112 + xc) * 256 + lane * 4);
    }
  }
  __syncthreads();
  int c2 = tid & 127, grp = tid >> 7;
  int oyl = grp >> 1, og = grp & 1;
  int rb = oyl * 2;
  float w0 = 1.f - fy;
  unsigned short* op = roi_sem + (((size_t)kb * NODES) + (2 * g + oyl) * OS) * 256 + c2 * 2;
  #pragma unroll
  for (int oxs = 0; oxs < 7; ++oxs) {
    int ox = og * 7 + oxs;
    float o0 = 0.f, o1 = 0.f;
    #pragma unroll
    for (int xi = 0; xi < 3; ++xi) {
      float xw = (xi == 0) ? (1.f - fx) : (xi == 1 ? 1.f : fx);
      const unsigned short* p0 = &slab[rb][2 * ox + xi][c2 * 2];
      const unsigned short* p1 = &slab[rb + 1][2 * ox + xi][c2 * 2];
      const unsigned short* p2 = &slab[rb + 2][2 * ox + xi][c2 * 2];
      o0 += xw * (w0 * bf2f(p0[0]) + bf2f(p1[0]) + fy * bf2f(p2[0]));
      o1 += xw * (w0 * bf2f(p0[1]) + bf2f(p1[1]) + fy * bf2f(p2[1]));
    }
    ushort2 v;
    v.x = (unsigned short)f2bf(o0 * 0.25f);
    v.y = (unsigned short)f2bf(o1 * 0.25f);
    *(ushort2*)(op + (size_t)ox * 256) = v;
  }
}

// ---------------- bn_relu + dual 3x3 conv, pos-split waves -> bn_aff_relu bf16 ----------------
// 8 waves = (pg in [0,4) owning filter-pos set {0,1,2}/{3,4}/{5,6}/{7,8}; ng in [0,2) owning
// oc-tiles {2ng, 2ng+1}). Each (pos,nt) weight frag read ONCE per block, direct from global
// (L2-resident). Input staged once per src in LDS (stride 268 -> ~2-way). Partial sums
// reduced across pg via LDS f32 tree. Cuts LDS instrs ~1.7x vs per-phase staging.
__global__ __launch_bounds__(512) void conv_ab_kernel(
    const unsigned short* __restrict__ roi_sem, const unsigned short* __restrict__ roif,
    const float* __restrict__ ss_sem, const float* __restrict__ ss_fpn,
    const float* __restrict__ ss_aff2, const short* __restrict__ wfrag,
    short* __restrict__ a_rel)
{
  __shared__ short inLDS[198 * 268];      // 106,128 B; rows 0..195 input, 196 zero pad
  __shared__ float scA[64], cmbA[64];
  const int k = blockIdx.x;
  const int tid = threadIdx.x;
  const int wave = tid >> 6, lane = tid & 63;
  const int l15 = lane & 15, lq = lane >> 4;
  const int pg = wave >> 1, ng = wave & 1;
  const int p0 = (pg == 0) ? 0 : (pg * 2 + 1);
  const int p1 = p0 + ((pg == 0) ? 3 : 2);

  if (tid < 64) { scA[tid] = ss_aff2[tid]; cmbA[tid] = ss_aff2[64 + tid]; }
  if (tid < 34) {
    bf16x8 z = {};
    *(bf16x8*)&inLDS[196 * 268 + tid * 8] = z;   // spills into row 197 scratch
  }

  int oyA[13], oxA[13];
  #pragma unroll
  for (int mt = 0; mt < 13; ++mt) {
    int j = mt * 16 + l15;
    int oy = j / 14;
    oyA[mt] = oy; oxA[mt] = j - oy * 14;
  }
  const int c0 = (tid & 31) * 8;

  f32x4 acc[13][2];
  #pragma unroll
  for (int mt = 0; mt < 13; ++mt) {
    acc[mt][0] = f32x4{0.f, 0.f, 0.f, 0.f};
    acc[mt][1] = f32x4{0.f, 0.f, 0.f, 0.f};
  }

  for (int src = 0; src < 2; ++src) {
    const unsigned short* inp = (src ? roif : roi_sem) + (size_t)k * NODES * CCH;
    const float* ss = src ? ss_fpn : ss_sem;
    f32x4 sc0 = *(const f32x4*)(ss + c0);
    f32x4 sc1 = *(const f32x4*)(ss + c0 + 4);
    f32x4 sh0 = *(const f32x4*)(ss + 256 + c0);
    f32x4 sh1 = *(const f32x4*)(ss + 256 + c0 + 4);
    __syncthreads();            // all waves done reading previous staging
    #pragma unroll
    for (int i = 0; i < 12; ++i) {
      int j = (tid >> 5) + i * 16;
      u16x8 v = *(const u16x8*)(inp + (size_t)j * 256 + c0);
      bf16x8 pk;
      #pragma unroll
      for (int u = 0; u < 4; ++u) pk[u] = f2bf(fmaxf(bf2f(v[u]) * sc0[u] + sh0[u], 0.f));
      #pragma unroll
      for (int u = 0; u < 4; ++u) pk[4 + u] = f2bf(fmaxf(bf2f(v[4 + u]) * sc1[u] + sh1[u], 0.f));
      *(bf16x8*)&inLDS[j * 268 + c0] = pk;
    }
    if (tid < 128) {
      int j = 192 + (tid >> 5);
      u16x8 v = *(const u16x8*)(inp + (size_t)j * 256 + c0);
      bf16x8 pk;
      #pragma unroll
      for (int u = 0; u < 4; ++u) pk[u] = f2bf(fmaxf(bf2f(v[u]) * sc0[u] + sh0[u], 0.f));
      #pragma unroll
      for (int u = 0; u < 4; ++u) pk[4 + u] = f2bf(fmaxf(bf2f(v[4 + u]) * sc1[u] + sh1[u], 0.f));
      *(bf16x8*)&inLDS[j * 268 + c0] = pk;
    }
    __syncthreads();

    for (int pos = p0; pos < p1; ++pos) {
      int ky = pos / 3 - 1, kx = pos % 3 - 1;       // wave-uniform
      int np[13];
      #pragma unroll
      for (int mt = 0; mt < 13; ++mt) {
        int ny = oyA[mt] + ky, nx = oxA[mt] + kx;
        bool v = ((unsigned)ny < 14u) & ((unsigned)nx < 14u) & ((mt * 16 + l15) < 196);
        np[mt] = v ? (ny * 14 + nx) : 196;
      }
      #pragma unroll
      for (int icc = 0; icc < 8; ++icc) {
        const short* wp = wfrag +
            ((size_t)((src * 72 + icc * 9 + pos) * 4 + ng * 2) * 64 + lane) * 8;
        bf16x8 b0 = *(const bf16x8*)wp;
        bf16x8 b1 = *(const bf16x8*)(wp + 512);
        #pragma unroll
        for (int mt = 0; mt < 13; ++mt) {
          bf16x8 a = *(const bf16x8*)&inLDS[np[mt] * 268 + icc * 32 + lq * 8];
          acc[mt][0] = MFMA16(a, b0, acc[mt][0], 0, 0, 0);
          acc[mt][1] = MFMA16(a, b1, acc[mt][1], 0, 0, 0);
        }
      }
    }
  }

  // ---- cross-pg reduction: pg1->buf0[ng], pg3->buf1[ng]; pg0+=buf0, pg2+=buf1;
  //      pg2->buf0[ng]; pg0+=buf0; pg0 applies bn_aff relu and writes a_rel ----
  float* red = (float*)inLDS;           // [2 buf][2 ng][196][32] f32 = 100,352 B
  __syncthreads();
  if (pg == 1 || pg == 3) {
    float* dst = red + (size_t)((pg >> 1) * 2 + ng) * 6272;
    #pragma unroll
    for (int mt = 0; mt < 13; ++mt)
      #pragma unroll
      for (int nn = 0; nn < 2; ++nn)
        #pragma unroll
        for (int r = 0; r < 4; ++r) {
          int j = mt * 16 + lq * 4 + r;
          if (j < 196) dst[j * 32 + nn * 16 + l15] = acc[mt][nn][r];
        }
  }
  __syncthreads();
  if (pg == 0 || pg == 2) {
    const float* sb = red + (size_t)((pg >> 1) * 2 + ng) * 6272;
    #pragma unroll
    for (int mt = 0; mt < 13; ++mt)
      #pragma unroll
      for (int nn = 0; nn < 2; ++nn)
        #pragma unroll
        for (int r = 0; r < 4; ++r) {
          int j = mt * 16 + lq * 4 + r;
          if (j < 196) acc[mt][nn][r] += sb[j * 32 + nn * 16 + l15];
        }
  }
  __syncthreads();
  if (pg == 2) {
    float* dst = red + (size_t)ng * 6272;
    #pragma unroll
    for (int mt = 0; mt < 13; ++mt)
      #pragma unroll
      for (int nn = 0; nn < 2; ++nn)
        #pragma unroll
        for (int r = 0; r < 4; ++r) {
          int j = mt * 16 + lq * 4 + r;
          if (j < 196) dst[j * 32 + nn * 16 + l15] = acc[mt][nn][r];
        }
  }
  __syncthreads();
  if (pg == 0) {
    const float* sb = red + (size_t)ng * 6272;
    short* op = a_rel + (size_t)k * 12544;
    #pragma unroll
    for (int mt = 0; mt < 13; ++mt)
      #pragma unroll
      for (int nn = 0; nn < 2; ++nn) {
        int oc = (ng * 2 + nn) * 16 + l15;
        float sa = scA[oc], cb = cmbA[oc];
        #pragma unroll
        for (int r = 0; r < 4; ++r) {
          int j = mt * 16 + lq * 4 + r;
          if (j < 196) {
            float t = acc[mt][nn][r] + sb[j * 32 + nn * 16 + l15];
            op[j * 64 + oc] = f2bf(fmaxf(t * sa + cb, 0.f));
          }
        }
      }
  }
}

// ---------------- fused graph kernel: aff+sigmoid+deg + xw1 + agg1 + agg2 + MFMA epilogue ----------------
__global__ __launch_bounds__(1024, 1) void graph_kernel(
    const short* __restrict__ a_rel, const short* __restrict__ wafrag,
    const float* __restrict__ aff_b, const short* __restrict__ g1wf,
    const float* __restrict__ g1b, const unsigned short* __restrict__ roif_bf,
    const short* __restrict__ g2wf, const float* __restrict__ g2b,
    const unsigned short* __restrict__ roi_sem, float* __restrict__ outp)
{
  __shared__ __align__(16) char smem[125840];
  const int tid = threadIdx.x, wave = tid >> 6, lane = tid & 63;
  const int l15 = lane & 15, lq = lane >> 4;
  const int k = blockIdx.x;

  char*  Ab   = smem;                       // [208][464 B] bf16 A^T (row j, col i)
  short* wa   = (short*)(smem + 96512);     // 26,624 B  [P0..P1]
  short* yfr  = (short*)(smem + 96512);     // 7,168 B   [post-P1, overlays wa]
  short* zsf  = (short*)(smem + 103680);    // 13,312 B  [post-P1, overlays wa]
  float* dsl  = (float*)(smem + 123136);    // 208 f32
  float* g1bl = (float*)(smem + 123968);    // 16 f32
  float* g2bl = (float*)(smem + 124032);    // 256 f32
  float* affb = (float*)(smem + 125056);    // 196 f32

  const bool wv13 = (wave < 13);
  const int jr  = wave * 16 + l15;
  const int jrc = min(jr, 195);
  const i32x4 z4 = {};

  // ---------- P0: a-frags to regs; stage wa; zero Ab pad cols; stage biases ----------
  bf16x8 af0 = {}, af1 = {};
  if (wv13) {
    const short* ap = a_rel + (size_t)k * 12544 + jrc * 64 + lq * 8;
    af0 = *(const bf16x8*)ap;
    af1 = *(const bf16x8*)(ap + 32);
  }
  {
    i32x4 w0 = ((const i32x4*)wafrag)[tid];
    i32x4 w1 = z4;
    if (tid < 640) w1 = ((const i32x4*)wafrag)[1024 + tid];
    if (tid < 832) {
      int r = tid >> 2, q = tid & 3;
      *(i32x4*)(Ab + r * 464 + 384 + q * 16) = z4;
    }
    if (tid < 196) affb[tid] = aff_b[tid];
    if (tid < 256) g2bl[tid] = g2b[tid];
    if (tid < 16)  g1bl[tid] = g1b[tid];
    ((i32x4*)wa)[tid] = w0;
    if (tid < 640) ((i32x4*)wa)[1024 + tid] = w1;
  }
  __syncthreads();

  // ---------- P1: aff 1x1 conv + sigmoid -> Ab; rowsum -> dsl ----------
  if (wv13) {
    float rsum[4] = {0.f, 0.f, 0.f, 0.f};
    #pragma unroll
    for (int n = 0; n < 13; ++n) {
      bf16x8 b0 = *(const bf16x8*)(wa + (n * 64 + lane) * 8);
      bf16x8 b1 = *(const bf16x8*)(wa + ((13 + n) * 64 + lane) * 8);
      f32x4 acc = {0.f, 0.f, 0.f, 0.f};
      acc = MFMA16(af0, b0, acc, 0, 0, 0);
      acc = MFMA16(af1, b1, acc, 0, 0, 0);
      int i = n * 16 + l15;
      bool iv = (i < 196);
      float bv = affb[iv ? i : 0];
      #pragma unroll
      for (int r = 0; r < 4; ++r) {
        float v = acc[r] + bv;
        float s = 1.f / (1.f + __expf(-v));
        if (iv) {
          rsum[r] += s;
          *(short*)(Ab + (wave * 16 + lq * 4 + r) * 464 + i * 2) = f2bf(s);
        }
      }
    }
    #pragma unroll
    for (int r = 0; r < 4; ++r) {
      float v = rsum[r];
      v += __shfl_xor(v, 1); v += __shfl_xor(v, 2);
      v += __shfl_xor(v, 4); v += __shfl_xor(v, 8);
      int j = wave * 16 + lq * 4 + r;
      if (l15 == 0 && j < 196) dsl[j] = rsqrtf(v);
    }
  }
  __syncthreads();

  // ---------- P2/P3: zero yfr+zsf; xw1 = X @ g1w (direct global frags) ----------
  *(i32x4*)(smem + 96512 + tid * 16) = z4;
  if (tid < 256) *(i32x4*)(smem + 96512 + (1024 + tid) * 16) = z4;
  f32x4 xacc = {0.f, 0.f, 0.f, 0.f};
  if (wv13) {
    const unsigned short* Xp = roif_bf + (size_t)k * 50176 + (size_t)jrc * 256 + lq * 8;
    #pragma unroll
    for (int ks = 0; ks < 8; ++ks) {
      bf16x8 xa = *(const bf16x8*)(Xp + ks * 32);
      bf16x8 xb = *(const bf16x8*)(g1wf + (ks * 64 + lane) * 8);
      xacc = MFMA16(xa, xb, xacc, 0, 0, 0);
    }
  }
  __syncthreads();

  // ---------- P4: y = dis*xw1 -> yfr B-frags ----------
  if (wv13) {
    #pragma unroll
    for (int r = 0; r < 4; ++r) {
      int i = wave * 16 + lq * 4 + r;
      if (i < 196) {
        float yv = dsl[i] * xacc[r];
        yfr[((i >> 5) * 64 + ((i >> 3) & 3) * 16 + l15) * 8 + (i & 7)] = f2bf(yv);
      }
    }
  }
  __syncthreads();

  // ---------- P5: agg1 ----------
  f32x4 g0 = {0.f, 0.f, 0.f, 0.f};
  if (wv13) {
    #pragma unroll
    for (int ks = 0; ks < 7; ++ks) {
      bf16x8 bb = *(const bf16x8*)(yfr + (ks * 64 + lane) * 8);
      bf16x8 a0 = *(const bf16x8*)(Ab + jr * 464 + ks * 64 + lq * 16);
      g0 = MFMA16(a0, bb, g0, 0, 0, 0);
    }
  }
  __syncthreads();
  if (wv13) {
    #pragma unroll
    for (int r = 0; r < 4; ++r) {
      int i = wave * 16 + lq * 4 + r;
      if (i < 196) {
        float d = dsl[i];
        float x1v = fmaxf(g0[r] * d + g1bl[l15], 0.f);
        yfr[((i >> 5) * 64 + ((i >> 3) & 3) * 16 + l15) * 8 + (i & 7)] = f2bf(d * x1v);
      }
    }
  }
  __syncthreads();

  // ---------- P6: agg2 -> zs (dis-scaled) -> zsf B-frags ----------
  if (wv13) {
    f32x4 z0 = {0.f, 0.f, 0.f, 0.f};
    #pragma unroll
    for (int ks = 0; ks < 7; ++ks) {
      bf16x8 bb = *(const bf16x8*)(yfr + (ks * 64 + lane) * 8);
      bf16x8 a0 = *(const bf16x8*)(Ab + jr * 464 + ks * 64 + lq * 16);
      z0 = MFMA16(a0, bb, z0, 0, 0, 0);
    }
    #pragma unroll
    for (int r = 0; r < 4; ++r) {
      int j = wave * 16 + lq * 4 + r;
      if (j < 196) {
        float zv = z0[r] * dsl[j];
        zsf[((j >> 4) * 64 + (l15 >> 3) * 16 + (j & 15)) * 8 + (l15 & 7)] = f2bf(zv);
      }
    }
  }
  __syncthreads();

  // ---------- P7: out[k,c,j] = mfma(w2_frag, zs_frag) + g2b[c] + roi_sem[k,j,c] ----------
  {
    bf16x8 wf = *(const bf16x8*)(g2wf + (wave * 64 + lane) * 8);
    const unsigned short* rsmk = roi_sem + (size_t)k * 50176;
    float* op = outp + (size_t)k * 50176;
    float gbv[4];
    #pragma unroll
    for (int r = 0; r < 4; ++r) gbv[r] = g2bl[wave * 16 + lq * 4 + r];
    #pragma unroll
    for (int jt = 0; jt < 13; ++jt) {
      bf16x8 zb = *(const bf16x8*)(zsf + (jt * 64 + lane) * 8);
      f32x4 d = {0.f, 0.f, 0.f, 0.f};
      d = MFMA16(wf, zb, d, 0, 0, 0);
      int j = jt * 16 + l15;
      if (j < 196) {
        #pragma unroll
        for (int r = 0; r < 4; ++r) {
          int c = wave * 16 + lq * 4 + r;
          op[(size_t)c * 196 + j] = d[r] + gbv[r] + bf2f(rsmk[(size_t)j * 256 + c]);
        }
      }
    }
  }
}

extern "C" void kernel_launch(void* const* d_in, const int* in_sizes, int n_in,
                              void* d_out, int out_size, void* d_ws, size_t ws_size,
                              hipStream_t stream) {
  const float* roi_feature = (const float*)d_in[0];
  const float* semantic    = (const float*)d_in[1];
  const float* boxes       = (const float*)d_in[2];
  const float* bn_sem_g = (const float*)d_in[3];
  const float* bn_sem_b = (const float*)d_in[4];
  const float* bn_sem_m = (const float*)d_in[5];
  const float* bn_sem_v = (const float*)d_in[6];
  const float* conv_sem_w = (const float*)d_in[7];
  const float* conv_sem_b = (const float*)d_in[8];
  const float* bn_fpn_g = (const float*)d_in[9];
  const float* bn_fpn_b = (const float*)d_in[10];
  const float* bn_fpn_m = (const float*)d_in[11];
  const float* bn_fpn_v = (const float*)d_in[12];
  const float* conv_fpn_w = (const float*)d_in[13];
  const float* conv_fpn_b = (const float*)d_in[14];
  const float* bn_aff_g = (const float*)d_in[15];
  const float* bn_aff_b = (const float*)d_in[16];
  const float* bn_aff_m = (const float*)d_in[17];
  const float* bn_aff_v = (const float*)d_in[18];
  const float* conv_aff_w = (const float*)d_in[19];
  const float* conv_aff_b = (const float*)d_in[20];
  const float* gcn1_w = (const float*)d_in[21];
  const float* gcn1_b = (const float*)d_in[22];
  const float* gcn2_w = (const float*)d_in[23];
  const float* gcn2_b = (const float*)d_in[24];

  const size_t FT = (size_t)KBOX * NODES * CCH;       // 12,845,056 elements
  unsigned short* ws16      = (unsigned short*)d_ws;
  unsigned short* semt_bf   = ws16;                    // FT shorts
  unsigned short* roif_bf   = semt_bf + FT;
  unsigned short* roi_sem_b = roif_bf + FT;
  short*          a_rel     = (short*)(roi_sem_b + FT);          // 3,211,264 shorts
  float*          ss_sem    = (float*)(a_rel + 3211264);         // 512
  float*          ss_fpn    = ss_sem + 512;                      // 512
  float*          ss_aff2   = ss_fpn + 512;                      // 128
  short*          wfrag     = (short*)(ss_aff2 + 128);           // 294,912
  short*          wafrag    = wfrag + 294912;                    // 13,312
  short*          g1wf      = wafrag + 13312;                    // 4,096
  short*          g2wf      = g1wf + 4096;                       // 8,192

  prep_kernel<<<256, 256, 0, stream>>>(
      bn_sem_g, bn_sem_b, bn_sem_m, bn_sem_v, conv_sem_w, conv_sem_b,
      bn_fpn_g, bn_fpn_b, bn_fpn_m, bn_fpn_v, conv_fpn_w, conv_fpn_b,
      bn_aff_g, bn_aff_b, bn_aff_m, bn_aff_v, conv_aff_w, gcn1_w, gcn2_w,
      ss_sem, ss_fpn, ss_aff2, wfrag, wafrag, g1wf, g2wf);

  transpose_bf16_kernel<<<4 * 196 * 4, 256, 0, stream>>>(semantic, semt_bf, 256, 12544);
  transpose_bf16_kernel<<<4 * 4 * 256, 256, 0, stream>>>(roi_feature, roif_bf, 256, 196);
  roi_align_kernel<<<KBOX * 7, 512, 0, stream>>>(semt_bf, boxes, roi_sem_b);
  conv_ab_kernel<<<KBOX, 512, 0, stream>>>(roi_sem_b, roif_bf, ss_sem, ss_fpn, ss_aff2,
                                           wfrag, a_rel);
  graph_kernel<<<KBOX, 1024, 0, stream>>>(a_rel, wafrag, conv_aff_b, g1wf, gcn1_b, roif_bf,
                                          g2wf, gcn2_b, roi_sem_b, (float*)d_out);
}